// Round 3
// baseline (116.362 us; speedup 1.0000x reference)
//
#include <hip/hip_runtime.h>
#include <hip/hip_bf16.h>

// Problem constants (from reference)
#define BB   4096
#define MM   200
#define DD   100
#define NENT 5000

// ws layout (bytes):
//   Pr  : bf16[5000][100] @ 0         (1,000,000 B) = sym@W[:, :D]^T + (gcn_w_bias+gcn_b)
//   PES : bf16[5000][200] @ 1,000,000 (2,000,000 B) = [Pe row | Sy row] interleaved per entity
//         PES[e][0..99]  = sym[e]@W[:, D:]^T
//         PES[e][100..199] = bf16(sym[e])

__device__ __forceinline__ float bf16lo(unsigned u) { return __uint_as_float(u << 16); }
__device__ __forceinline__ float bf16hi(unsigned u) { return __uint_as_float(u & 0xffff0000u); }
__device__ __forceinline__ unsigned short f2bf(float f) {
    unsigned u = __float_as_uint(f);
    return (unsigned short)((u + 0x7fffu + ((u >> 16) & 1u)) >> 16);
}

// ---------------------------------------------------------------------------
// Kernel A: project the 5000 usable symbol rows through both halves of W.
// ---------------------------------------------------------------------------
__global__ __launch_bounds__(256) void precompute_kernel(
    const float* __restrict__ sym, const float* __restrict__ W,
    const float* __restrict__ wb, const float* __restrict__ gb,
    unsigned short* __restrict__ Pr, unsigned short* __restrict__ PES)
{
    __shared__ unsigned short Wt[200 * 102];
    const int tid = threadIdx.x;
    for (int j = tid; j < 20000; j += 256) {
        int d = j / 200, k = j % 200;
        Wt[k * 102 + d] = f2bf(W[j]);
    }
    __syncthreads();

    const int i = blockIdx.x * 256 + tid;
    if (i >= NENT * 50) return;
    const int e = i / 50, dp = i % 50;
    const float* se = sym + e * DD;

    float pr0 = 0.f, pr1 = 0.f, pe0 = 0.f, pe1 = 0.f;
    for (int k = 0; k < 100; k++) {
        float a = se[k];
        unsigned w01 = *(const unsigned*)&Wt[k * 102 + 2 * dp];
        unsigned w23 = *(const unsigned*)&Wt[(k + 100) * 102 + 2 * dp];
        pr0 = fmaf(a, bf16lo(w01), pr0);
        pr1 = fmaf(a, bf16hi(w01), pr1);
        pe0 = fmaf(a, bf16lo(w23), pe0);
        pe1 = fmaf(a, bf16hi(w23), pe1);
    }
    const int d0 = 2 * dp;
    pr0 += wb[d0]     + gb[d0];
    pr1 += wb[d0 + 1] + gb[d0 + 1];

    *(unsigned*)&Pr[e * DD + d0] =
        (unsigned)f2bf(pr0) | ((unsigned)f2bf(pr1) << 16);
    *(unsigned*)&PES[e * 2 * DD + d0] =
        (unsigned)f2bf(pe0) | ((unsigned)f2bf(pe1) << 16);
    *(unsigned*)&PES[e * 2 * DD + DD + d0] =
        (unsigned)f2bf(se[d0]) | ((unsigned)f2bf(se[d0 + 1]) << 16);
}

// ---------------------------------------------------------------------------
// Kernel B: one block per batch row. No out storage — recompute.
//   Phase A (thread=m): logit_m = attn_w . lrelu(Pr[rel_m] + Pe[ent_m]),
//     streamed from L2 into registers.
//   Softmax in registers (shuffles), store {ev, co} + {rel|ent} to LDS.
//   Phase B (thread=(g,dp)): recompute out[m][dpair], accumulate
//     oa += ev*x and nb += co*Sy; divide by sum once at the end.
// ---------------------------------------------------------------------------
__global__ __launch_bounds__(256, 8) void main_kernel(
    const int*  __restrict__ conn, const int* __restrict__ target,
    const float* __restrict__ sym, const float* __restrict__ co,
    const unsigned short* __restrict__ Pr, const unsigned short* __restrict__ PES,
    const float* __restrict__ attn_w,
    const float* __restrict__ gate_w, const float* __restrict__ gate_wb,
    const float* __restrict__ gate_b,
    float* __restrict__ outp)
{
    __shared__ unsigned idx_s[MM];       // rel | ent<<16
    __shared__ float    wc_s[2 * MM];    // [2m]=exp(l-max), [2m+1]=co_weight
    __shared__ float    red[8];
    __shared__ float    part[2 * 5 * DD];// 5-way partials: oa then nb

    const int t = threadIdx.x;
    const int b = blockIdx.x;
    const int* cb = conn + b * (MM * 3);

    // ---- load indices, issue scattered co gather early
    float co_reg = 0.f;
    int r_own = 0, e_own = 0;
    if (t < MM) {
        r_own = cb[t * 3 + 1];
        e_own = cb[t * 3 + 2];
        idx_s[t] = (unsigned)r_own | ((unsigned)e_own << 16);
        int tgt = target[b * 2];                       // uniform
        co_reg = co[(long)e_own * NENT + tgt];         // scattered, long latency
    }

    // ---- Phase A: attention logit for own m (register-only, no barrier)
    float lacc = 0.f;
    if (t < MM) {
        const uint2* pr2 = (const uint2*)(Pr + r_own * DD);        // 200B row, 8B-aligned
        const uint2* pe2 = (const uint2*)(PES + e_own * 2 * DD);   // Pe = first 200B
        #pragma unroll
        for (int i = 0; i < 25; ++i) {
            uint2 a = pr2[i];
            uint2 c = pe2[i];
            float x0 = bf16lo(a.x) + bf16lo(c.x);
            float x1 = bf16hi(a.x) + bf16hi(c.x);
            float x2 = bf16lo(a.y) + bf16lo(c.y);
            float x3 = bf16hi(a.y) + bf16hi(c.y);
            x0 = fmaxf(x0, 0.01f * x0);
            x1 = fmaxf(x1, 0.01f * x1);
            x2 = fmaxf(x2, 0.01f * x2);
            x3 = fmaxf(x3, 0.01f * x3);
            lacc = fmaf(x0, attn_w[4 * i],     lacc);
            lacc = fmaf(x1, attn_w[4 * i + 1], lacc);
            lacc = fmaf(x2, attn_w[4 * i + 2], lacc);
            lacc = fmaf(x3, attn_w[4 * i + 3], lacc);
        }
        // attn_b omitted: constant shift cancels in softmax
    }

    // ---- softmax over 200 logits (values live in registers)
    const int lane = t & 63, wid = t >> 6;
    float v = (t < MM) ? lacc : -3.0e38f;
    for (int off = 32; off >= 1; off >>= 1) v = fmaxf(v, __shfl_xor(v, off));
    if (lane == 0) red[wid] = v;
    __syncthreads();                                   // S1
    float gmax = fmaxf(fmaxf(red[0], red[1]), fmaxf(red[2], red[3]));
    float ev = (t < MM) ? __expf(lacc - gmax) : 0.f;
    float s = ev;
    for (int off = 32; off >= 1; off >>= 1) s += __shfl_xor(s, off);
    if (lane == 0) red[4 + wid] = s;
    if (t < MM) {
        wc_s[2 * t]     = ev;                          // unnormalized weight
        wc_s[2 * t + 1] = co_reg;
    }
    __syncthreads();                                   // S2: red[4..7], wc_s, idx_s
    float gsum = (red[4] + red[5]) + (red[6] + red[7]);

    // ---- Phase B: recompute + accumulate. t = g*50 + dp.
    const int g = t / 50, dp = t % 50;
    const bool act = (t < 250);
    float oa0 = 0.f, oa1 = 0.f, nb0 = 0.f, nb1 = 0.f;
    if (act) {
        #pragma unroll 8
        for (int it = 0; it < 40; ++it) {
            int m = g + 5 * it;
            unsigned ir = idx_s[m];                    // ~broadcast within wave
            int r = ir & 0xffff, e = ir >> 16;
            float2 wcv = *(const float2*)&wc_s[2 * m]; // {ev, co}, broadcast
            unsigned pru = *(const unsigned*)(Pr + r * DD + 2 * dp);
            const unsigned short* pes = PES + e * 2 * DD;
            unsigned peu = *(const unsigned*)(pes + 2 * dp);        // Pe
            unsigned syu = *(const unsigned*)(pes + DD + 2 * dp);   // Sy (+200B)
            float x0 = bf16lo(pru) + bf16lo(peu);
            float x1 = bf16hi(pru) + bf16hi(peu);
            x0 = fmaxf(x0, 0.01f * x0);
            x1 = fmaxf(x1, 0.01f * x1);
            oa0 = fmaf(wcv.x, x0, oa0);
            oa1 = fmaf(wcv.x, x1, oa1);
            nb0 = fmaf(wcv.y, bf16lo(syu), nb0);
            nb1 = fmaf(wcv.y, bf16hi(syu), nb1);
        }
    }
    float inv = 1.f / gsum;
    oa0 *= inv; oa1 *= inv;

    // ---- 5-way reduction over g (float2 stores, 2-way bank alias = free)
    if (act) {
        *(float2*)&part[g * DD + 2 * dp]            = make_float2(oa0, oa1);
        *(float2*)&part[5 * DD + g * DD + 2 * dp]   = make_float2(nb0, nb1);
    }
    __syncthreads();                                   // S3

    float oa = 0.f, nbv = 0.f;
    if (t < DD) {
        #pragma unroll
        for (int g2 = 0; g2 < 5; ++g2) {
            oa  += part[g2 * DD + t];
            nbv += part[5 * DD + g2 * DD + t];
        }
    }

    // ---- gate = sigmoid(dot(oa, gate_w) + gwb + gb)
    float p = (t < DD) ? oa * gate_w[t] : 0.f;
    for (int off = 32; off >= 1; off >>= 1) p += __shfl_xor(p, off);
    if (lane == 0) red[wid] = p;                       // safe: old red read pre-S3
    __syncthreads();                                   // S4
    float dot = (red[0] + red[1]) + (red[2] + red[3]);
    float gt = 1.f / (1.f + __expf(-(dot + gate_wb[0] + gate_b[0])));

    if (t < DD) {
        int s_self = cb[0];                            // uniform
        float self_v = sym[s_self * DD + t];           // f32, exact
        outp[b * DD + t] = oa * gt + self_v * (1.f - gt) + nbv;
    }
}

extern "C" void kernel_launch(void* const* d_in, const int* in_sizes, int n_in,
                              void* d_out, int out_size, void* d_ws, size_t ws_size,
                              hipStream_t stream) {
    const int*   conn    = (const int*)  d_in[0];
    const int*   target  = (const int*)  d_in[1];
    const float* sym     = (const float*)d_in[2];
    const float* co      = (const float*)d_in[3];
    const float* W       = (const float*)d_in[4];
    const float* wb      = (const float*)d_in[5];
    const float* gb      = (const float*)d_in[6];
    const float* attn_w  = (const float*)d_in[7];
    // d_in[8] = attn_w_bias: cancels in softmax, unused
    const float* gate_w  = (const float*)d_in[9];
    const float* gate_wb = (const float*)d_in[10];
    const float* gate_b  = (const float*)d_in[11];

    unsigned short* Pr  = (unsigned short*)d_ws;
    unsigned short* PES = (unsigned short*)((char*)d_ws + 1000000);

    precompute_kernel<<<(NENT * 50 + 255) / 256, 256, 0, stream>>>(
        sym, W, wb, gb, Pr, PES);

    main_kernel<<<BB, 256, 0, stream>>>(
        conn, target, sym, co, Pr, PES,
        attn_w, gate_w, gate_wb, gate_b, (float*)d_out);
}

// Round 4
// 89.286 us; speedup vs baseline: 1.3032x; 1.3032x over previous
//
#include <hip/hip_runtime.h>
#include <hip/hip_bf16.h>

// Problem constants (from reference)
#define BB   4096
#define MM   200
#define DD   100
#define NENT 5000
#define LDW  51    // out row stride in u32 (odd -> conflict-free)

// ws layout (bytes):
//   Pr  : bf16[5000][100] @ 0         = sym@W[:, :D]^T + (gcn_w_bias+gcn_b)
//   PES : bf16[5000][200] @ 1,000,000 = [Pe row | Sy row] per entity
//         PES[e][0..99]    = sym[e]@W[:, D:]^T
//         PES[e][100..199] = bf16(sym[e])

__device__ __forceinline__ float bf16lo(unsigned u) { return __uint_as_float(u << 16); }
__device__ __forceinline__ float bf16hi(unsigned u) { return __uint_as_float(u & 0xffff0000u); }
__device__ __forceinline__ unsigned short f2bf(float f) {
    unsigned u = __float_as_uint(f);
    return (unsigned short)((u + 0x7fffu + ((u >> 16) & 1u)) >> 16);
}

// ---------------------------------------------------------------------------
// Kernel A: project the 5000 usable symbol rows through both halves of W.
// ---------------------------------------------------------------------------
__global__ __launch_bounds__(256) void precompute_kernel(
    const float* __restrict__ sym, const float* __restrict__ W,
    const float* __restrict__ wb, const float* __restrict__ gb,
    unsigned short* __restrict__ Pr, unsigned short* __restrict__ PES)
{
    __shared__ unsigned short Wt[200 * 102];
    const int tid = threadIdx.x;
    for (int j = tid; j < 20000; j += 256) {
        int d = j / 200, k = j % 200;
        Wt[k * 102 + d] = f2bf(W[j]);
    }
    __syncthreads();

    const int i = blockIdx.x * 256 + tid;
    if (i >= NENT * 50) return;
    const int e = i / 50, dp = i % 50;
    const float* se = sym + e * DD;

    float pr0 = 0.f, pr1 = 0.f, pe0 = 0.f, pe1 = 0.f;
    for (int k = 0; k < 100; k++) {
        float a = se[k];
        unsigned w01 = *(const unsigned*)&Wt[k * 102 + 2 * dp];
        unsigned w23 = *(const unsigned*)&Wt[(k + 100) * 102 + 2 * dp];
        pr0 = fmaf(a, bf16lo(w01), pr0);
        pr1 = fmaf(a, bf16hi(w01), pr1);
        pe0 = fmaf(a, bf16lo(w23), pe0);
        pe1 = fmaf(a, bf16hi(w23), pe1);
    }
    const int d0 = 2 * dp;
    pr0 += wb[d0]     + gb[d0];
    pr1 += wb[d0 + 1] + gb[d0 + 1];

    *(unsigned*)&Pr[e * DD + d0] =
        (unsigned)f2bf(pr0) | ((unsigned)f2bf(pr1) << 16);
    *(unsigned*)&PES[e * 2 * DD + d0] =
        (unsigned)f2bf(pe0) | ((unsigned)f2bf(pe1) << 16);
    *(unsigned*)&PES[e * 2 * DD + DD + d0] =
        (unsigned)f2bf(se[d0]) | ((unsigned)f2bf(se[d0 + 1]) << 16);
}

// ---------------------------------------------------------------------------
// Kernel B: one block per batch row; single pass over all 200 m.
// Coalesced (m-across-iters, dp-across-lanes) gathers; out in LDS (bf16x2).
// 6 barriers per block total.
// ---------------------------------------------------------------------------
__global__ __launch_bounds__(256) void main_kernel(
    const int*  __restrict__ conn, const int* __restrict__ target,
    const float* __restrict__ sym, const float* __restrict__ co,
    const unsigned short* __restrict__ Pr, const unsigned short* __restrict__ PES,
    const float* __restrict__ attn_w,
    const float* __restrict__ gate_w, const float* __restrict__ gate_wb,
    const float* __restrict__ gate_b,
    float* __restrict__ outp)
{
    __shared__ unsigned out_lds[MM * LDW];   // 40.8 KB packed bf16 pairs
    __shared__ float    aw_s[DD];            // attn_w staged
    __shared__ unsigned idx_s[MM];           // rel | ent<<16
    __shared__ float    wc_s[2 * MM];        // [2m]=exp(l-max), [2m+1]=co_weight
    __shared__ float    red[8];
    __shared__ float    part[2 * 5 * DD];    // 5-way partials: oa then nb

    const int t = threadIdx.x;
    const int b = blockIdx.x;
    const int* cb = conn + b * (MM * 3);
    const int lane = t & 63, wid = t >> 6;

    // ---- indices + early-issued scattered co gather (kept in register)
    float co_reg = 0.f;
    if (t < MM) {
        int r = cb[t * 3 + 1];
        int e = cb[t * 3 + 2];
        idx_s[t] = (unsigned)r | ((unsigned)e << 16);
        int tgt = target[b * 2];                     // uniform
        co_reg = co[(long)e * NENT + tgt];           // scattered, long latency
    }
    if (t < DD) aw_s[t] = attn_w[t];
    __syncthreads();                                 // S0: idx_s, aw_s

    // ---- Phase 2: out[m][dp] = lrelu(Pr[rel]+Pe[ent]), coalesced gathers
    const int g = t / 50, dp = t % 50;
    const bool act = (t < 250);
    if (act) {
        #pragma unroll 8
        for (int it = 0; it < 40; ++it) {
            int m = g + 5 * it;
            unsigned ir = idx_s[m];                  // broadcast-ish
            int r = ir & 0xffff, e = ir >> 16;
            unsigned pru = *(const unsigned*)(Pr + r * DD + 2 * dp);
            unsigned peu = *(const unsigned*)(PES + e * 2 * DD + 2 * dp);
            float x0 = bf16lo(pru) + bf16lo(peu);
            float x1 = bf16hi(pru) + bf16hi(peu);
            x0 = fmaxf(x0, 0.01f * x0);
            x1 = fmaxf(x1, 0.01f * x1);
            __hip_bfloat162 h = __float22bfloat162_rn(make_float2(x0, x1));
            out_lds[m * LDW + dp] = *(unsigned*)&h;
        }
    }
    __syncthreads();                                 // S1: out ready

    // ---- logits: thread = m, stride-51 rows -> conflict-free
    float lacc = 0.f;
    if (t < MM) {
        const unsigned* row = &out_lds[t * LDW];
        #pragma unroll 10
        for (int i = 0; i < 50; ++i) {
            unsigned u = row[i];
            lacc = fmaf(bf16lo(u), aw_s[2 * i],     lacc);
            lacc = fmaf(bf16hi(u), aw_s[2 * i + 1], lacc);
        }
        wc_s[2 * t + 1] = co_reg;                    // stash co alongside
    }
    // attn_b omitted: constant shift cancels in softmax

    // ---- softmax over 200 register logits
    float v = (t < MM) ? lacc : -3.0e38f;
    for (int off = 32; off >= 1; off >>= 1) v = fmaxf(v, __shfl_xor(v, off));
    if (lane == 0) red[wid] = v;
    __syncthreads();                                 // S2: red max + wc co
    float gmax = fmaxf(fmaxf(red[0], red[1]), fmaxf(red[2], red[3]));
    float ev = (t < MM) ? __expf(lacc - gmax) : 0.f;
    float s = ev;
    for (int off = 32; off >= 1; off >>= 1) s += __shfl_xor(s, off);
    if (lane == 0) red[4 + wid] = s;
    if (t < MM) wc_s[2 * t] = ev;                    // unnormalized weight
    __syncthreads();                                 // S3: red sum + wc ev
    float gsum = (red[4] + red[5]) + (red[6] + red[7]);

    // ---- Phase 4: oa += ev*out (LDS), nb += co*Sy (L2 gather, coalesced)
    float oa0 = 0.f, oa1 = 0.f, nb0 = 0.f, nb1 = 0.f;
    if (act) {
        #pragma unroll 8
        for (int it = 0; it < 40; ++it) {
            int m = g + 5 * it;
            float2 wcv = *(const float2*)&wc_s[2 * m];  // {ev, co} broadcast
            unsigned u = out_lds[m * LDW + dp];
            oa0 = fmaf(wcv.x, bf16lo(u), oa0);
            oa1 = fmaf(wcv.x, bf16hi(u), oa1);
            int e = idx_s[m] >> 16;
            unsigned su = *(const unsigned*)(PES + e * 2 * DD + DD + 2 * dp);
            nb0 = fmaf(wcv.y, bf16lo(su), nb0);
            nb1 = fmaf(wcv.y, bf16hi(su), nb1);
        }
    }
    float inv = 1.f / gsum;
    oa0 *= inv; oa1 *= inv;

    // ---- 5-way reduction over g
    if (act) {
        *(float2*)&part[g * DD + 2 * dp]          = make_float2(oa0, oa1);
        *(float2*)&part[5 * DD + g * DD + 2 * dp] = make_float2(nb0, nb1);
    }
    __syncthreads();                                 // S4: partials ready

    float oa = 0.f, nbv = 0.f;
    if (t < DD) {
        #pragma unroll
        for (int g2 = 0; g2 < 5; ++g2) {
            oa  += part[g2 * DD + t];
            nbv += part[5 * DD + g2 * DD + t];
        }
    }

    // ---- gate = sigmoid(dot(oa, gate_w) + gwb + gb)
    float p = (t < DD) ? oa * gate_w[t] : 0.f;
    for (int off = 32; off >= 1; off >>= 1) p += __shfl_xor(p, off);
    if (lane == 0) red[wid] = p;
    __syncthreads();                                 // S5
    float dot = (red[0] + red[1]) + (red[2] + red[3]);
    float gt = 1.f / (1.f + __expf(-(dot + gate_wb[0] + gate_b[0])));

    if (t < DD) {
        int s_self = cb[0];                          // uniform
        float self_v = sym[s_self * DD + t];         // f32, exact
        outp[b * DD + t] = oa * gt + self_v * (1.f - gt) + nbv;
    }
}

extern "C" void kernel_launch(void* const* d_in, const int* in_sizes, int n_in,
                              void* d_out, int out_size, void* d_ws, size_t ws_size,
                              hipStream_t stream) {
    const int*   conn    = (const int*)  d_in[0];
    const int*   target  = (const int*)  d_in[1];
    const float* sym     = (const float*)d_in[2];
    const float* co      = (const float*)d_in[3];
    const float* W       = (const float*)d_in[4];
    const float* wb      = (const float*)d_in[5];
    const float* gb      = (const float*)d_in[6];
    const float* attn_w  = (const float*)d_in[7];
    // d_in[8] = attn_w_bias: cancels in softmax, unused
    const float* gate_w  = (const float*)d_in[9];
    const float* gate_wb = (const float*)d_in[10];
    const float* gate_b  = (const float*)d_in[11];

    unsigned short* Pr  = (unsigned short*)d_ws;
    unsigned short* PES = (unsigned short*)((char*)d_ws + 1000000);

    precompute_kernel<<<(NENT * 50 + 255) / 256, 256, 0, stream>>>(
        sym, W, wb, gb, Pr, PES);

    main_kernel<<<BB, 256, 0, stream>>>(
        conn, target, sym, co, Pr, PES,
        attn_w, gate_w, gate_wb, gate_b, (float*)d_out);
}

// Round 6
// 70.306 us; speedup vs baseline: 1.6551x; 1.2700x over previous
//
#include <hip/hip_runtime.h>

// Problem constants
#define BB   4096
#define MM   200
#define DD   100
#define NENT 5000
#define CH   50     // m-chunk for online softmax
#define NCH  4
#define LPW  27     // logit-partial row stride (f32, odd)
#define PTW  101    // final-partial row stride (f32, odd)

typedef _Float16 f16x2 __attribute__((ext_vector_type(2)));
typedef unsigned uint2v __attribute__((ext_vector_type(2)));

#if defined(__has_builtin)
#if __has_builtin(__builtin_amdgcn_fdot2)
#define HAS_FDOT2 1
#endif
#endif

__device__ __forceinline__ f16x2 uh(unsigned u) { return __builtin_bit_cast(f16x2, u); }
__device__ __forceinline__ float2 h2f(f16x2 h) { return make_float2((float)h.x, (float)h.y); }

// ws layout (bytes):
//   Pr  : f16[5000][100] @ 0         = sym@W[:, :D]^T + (gcn_w_bias+gcn_b)
//   PES : f16[5000][200] @ 1,000,000 = [Pe row | sym row] per entity

// ---------------------------------------------------------------------------
// Kernel A: project the 5000 usable symbol rows through both halves of W.
// ---------------------------------------------------------------------------
__global__ __launch_bounds__(256) void precompute_kernel(
    const float* __restrict__ sym, const float* __restrict__ W,
    const float* __restrict__ wb, const float* __restrict__ gb,
    _Float16* __restrict__ Pr, _Float16* __restrict__ PES)
{
    __shared__ _Float16 Wt[200 * 102];
    const int tid = threadIdx.x;
    for (int j = tid; j < 20000; j += 256) {
        int d = j / 200, k = j % 200;
        Wt[k * 102 + d] = (_Float16)W[j];
    }
    __syncthreads();

    const int i = blockIdx.x * 256 + tid;
    if (i >= NENT * 50) return;
    const int e = i / 50, dp = i % 50;
    const float* se = sym + e * DD;

    float pr0 = 0.f, pr1 = 0.f, pe0 = 0.f, pe1 = 0.f;
    for (int k = 0; k < 100; k++) {
        float a = se[k];
        f16x2 w01 = *(const f16x2*)&Wt[k * 102 + 2 * dp];
        f16x2 w23 = *(const f16x2*)&Wt[(k + 100) * 102 + 2 * dp];
        pr0 = fmaf(a, (float)w01.x, pr0);
        pr1 = fmaf(a, (float)w01.y, pr1);
        pe0 = fmaf(a, (float)w23.x, pe0);
        pe1 = fmaf(a, (float)w23.y, pe1);
    }
    const int d0 = 2 * dp;
    pr0 += wb[d0]     + gb[d0];
    pr1 += wb[d0 + 1] + gb[d0 + 1];

    *(f16x2*)&Pr[e * DD + d0]           = f16x2{(_Float16)pr0, (_Float16)pr1};
    *(f16x2*)&PES[e * 2 * DD + d0]      = f16x2{(_Float16)pe0, (_Float16)pe1};
    *(f16x2*)&PES[e * 2 * DD + DD + d0] = f16x2{(_Float16)se[d0], (_Float16)se[d0 + 1]};
}

// ---------------------------------------------------------------------------
// Kernel B: one block per batch row. CH=50 online-softmax chunks.
// Thread map: t = g*25 + dq, g in [0,10), dq in [0,25) -> d = 4dq..4dq+3.
// Phase2 (packed f16 math): x = lrelu(Pr[rel]+Pe[ent]) kept in regs,
//   logit partial -> lp_s, neighbor sum fused (softmax-independent).
// Softmax: wave-redundant shfl reduce; weights fetched via __shfl(ev, ml).
// ---------------------------------------------------------------------------
__global__ __launch_bounds__(256, 6) void main_kernel(
    const int*  __restrict__ conn, const int* __restrict__ target,
    const float* __restrict__ sym, const float* __restrict__ co,
    const _Float16* __restrict__ Pr, const _Float16* __restrict__ PES,
    const float* __restrict__ attn_w,
    const float* __restrict__ gate_w, const float* __restrict__ gate_wb,
    const float* __restrict__ gate_b,
    float* __restrict__ outp)
{
    __shared__ float    scratch[2 * 10 * PTW];  // 8080 B: lp_s (1350 f32) / part
    __shared__ unsigned idx_s[MM];              // rel | ent<<16
    __shared__ float    co_s[MM];
    __shared__ float    l_s[CH];
    __shared__ float    red[4];
    float* lp_s = scratch;                      // [CH][LPW]
    float* part = scratch;                      // [20][PTW] (aliased, post-lp)

    const int t = threadIdx.x;
    const int b = blockIdx.x;
    const int* cb = conn + b * (MM * 3);
    const int lane = t & 63, wid = t >> 6;

    // ---- indices + scattered co gather
    if (t < MM) {
        int r = cb[t * 3 + 1];
        int e = cb[t * 3 + 2];
        idx_s[t] = (unsigned)r | ((unsigned)e << 16);
        int tgt = target[b * 2];                     // uniform
        co_s[t] = co[(long)e * NENT + tgt];          // scattered
    }
    __syncthreads();                                 // S0

    const int g = t / 25, dq = t % 25;
    const bool act = (t < 250);

    // attn_w slice for this thread's 4 d's (fixed across all iters)
    float4 awf = *(const float4*)&attn_w[4 * dq];
#ifdef HAS_FDOT2
    f16x2 aw01 = f16x2{(_Float16)awf.x, (_Float16)awf.y};
    f16x2 aw23 = f16x2{(_Float16)awf.z, (_Float16)awf.w};
#endif
    const _Float16 slope = (_Float16)0.01f;

    float oa0 = 0.f, oa1 = 0.f, oa2 = 0.f, oa3 = 0.f;
    f16x2 nb01 = f16x2{(_Float16)0.f, (_Float16)0.f};
    f16x2 nb23 = nb01;
    float run_max = -3.0e38f, run_sum = 0.f;
    uint2v xs[5];                                    // packed f16 x, per chunk

    for (int c = 0; c < NCH; ++c) {
        // ---- Phase 2: gather + lrelu (packed f16), logit partial, nb
        if (act) {
            #pragma unroll
            for (int it = 0; it < 5; ++it) {
                int ml = g + 10 * it;
                int m = c * CH + ml;
                unsigned ir = idx_s[m];
                int r = ir & 0xffff, e = ir >> 16;
                uint2v pru = *(const uint2v*)(Pr + r * DD + 4 * dq);
                uint2v peu = *(const uint2v*)(PES + e * 2 * DD + 4 * dq);
                uint2v syu = *(const uint2v*)(PES + e * 2 * DD + DD + 4 * dq);
                f16x2 x01 = uh(pru.x) + uh(peu.x);
                f16x2 x23 = uh(pru.y) + uh(peu.y);
                x01 = __builtin_elementwise_max(x01, x01 * slope);  // leaky relu
                x23 = __builtin_elementwise_max(x23, x23 * slope);
                xs[it].x = __builtin_bit_cast(unsigned, x01);
                xs[it].y = __builtin_bit_cast(unsigned, x23);
                float lp;
#ifdef HAS_FDOT2
                lp = __builtin_amdgcn_fdot2(x01, aw01, 0.0f, false);
                lp = __builtin_amdgcn_fdot2(x23, aw23, lp, false);
#else
                float2 f01 = h2f(x01), f23 = h2f(x23);
                lp = f01.x * awf.x + f01.y * awf.y + f23.x * awf.z + f23.y * awf.w;
#endif
                lp_s[ml * LPW + dq] = lp;
                // neighbor sum (softmax-independent): packed f16 fma
                _Float16 coh = (_Float16)co_s[m];
                f16x2 co2 = f16x2{coh, coh};
                nb01 = co2 * uh(syu.x) + nb01;
                nb23 = co2 * uh(syu.y) + nb23;
            }
        }
        __syncthreads();                             // A: lp_s ready

        // ---- logits finish: t<200 -> (ml, quarter), 4-lane shfl reduce
        if (t < 4 * CH) {
            int ml = t >> 2, q = t & 3;
            const float* row = &lp_s[ml * LPW + ((q == 0) ? 0 : 7 + 6 * (q - 1))];
            float s = row[0] + row[1] + row[2] + row[3] + row[4] + row[5];
            if (q == 0) s += row[6];
            s += __shfl_xor(s, 1);
            s += __shfl_xor(s, 2);
            if (q == 0) l_s[ml] = s;
        }
        __syncthreads();                             // B: l_s ready

        // ---- wave-redundant online softmax (no more barriers)
        float lv = (lane < CH) ? l_s[lane] : -3.0e38f;
        float mx = lv;
        for (int off = 32; off >= 1; off >>= 1) mx = fmaxf(mx, __shfl_xor(mx, off));
        float new_max = fmaxf(run_max, mx);
        float scale = __expf(run_max - new_max);     // chunk 0: exp(-inf)=0
        float ev = (lane < CH) ? __expf(lv - new_max) : 0.f;
        float cs = ev;
        for (int off = 32; off >= 1; off >>= 1) cs += __shfl_xor(cs, off);
        run_sum = run_sum * scale + cs;
        run_max = new_max;
        oa0 *= scale; oa1 *= scale; oa2 *= scale; oa3 *= scale;

        // ---- Phase 4: weighted sum from registers, weights via shfl
        if (act) {
            #pragma unroll
            for (int it = 0; it < 5; ++it) {
                int ml = g + 10 * it;
                float w = __shfl(ev, ml);            // lane ml of same wave
                float2 f01 = h2f(uh(xs[it].x));
                float2 f23 = h2f(uh(xs[it].y));
                oa0 = fmaf(w, f01.x, oa0);
                oa1 = fmaf(w, f01.y, oa1);
                oa2 = fmaf(w, f23.x, oa2);
                oa3 = fmaf(w, f23.y, oa3);
            }
        }
        // next chunk's phase2 writes lp_s: last reads were pre-B -> safe
    }

    // ---- 10-way g-reduction (part aliases lp_s; last lp read pre-B_3)
    if (act) {
        float* po = &part[g * PTW + 4 * dq];
        po[0] = oa0; po[1] = oa1; po[2] = oa2; po[3] = oa3;
        float2 n01 = h2f(nb01), n23 = h2f(nb23);
        float* pn = &part[(10 + g) * PTW + 4 * dq];
        pn[0] = n01.x; pn[1] = n01.y; pn[2] = n23.x; pn[3] = n23.y;
    }
    __syncthreads();                                 // F

    float inv = 1.f / run_sum;
    float oaf = 0.f, nbf = 0.f;
    if (t < DD) {
        #pragma unroll
        for (int g2 = 0; g2 < 10; ++g2) {
            oaf += part[g2 * PTW + t];
            nbf += part[(10 + g2) * PTW + t];
        }
        oaf *= inv;
    }

    // ---- gate = sigmoid(dot(oaf, gate_w) + gwb + gb)
    float p = (t < DD) ? oaf * gate_w[t] : 0.f;
    for (int off = 32; off >= 1; off >>= 1) p += __shfl_xor(p, off);
    if (lane == 0) red[wid] = p;
    __syncthreads();                                 // G
    float dot = (red[0] + red[1]) + (red[2] + red[3]);
    float gt = 1.f / (1.f + __expf(-(dot + gate_wb[0] + gate_b[0])));

    if (t < DD) {
        float self_v = sym[cb[0] * DD + t];          // f32, exact
        outp[b * DD + t] = oaf * gt + self_v * (1.f - gt) + nbf;
    }
}

extern "C" void kernel_launch(void* const* d_in, const int* in_sizes, int n_in,
                              void* d_out, int out_size, void* d_ws, size_t ws_size,
                              hipStream_t stream) {
    const int*   conn    = (const int*)  d_in[0];
    const int*   target  = (const int*)  d_in[1];
    const float* sym     = (const float*)d_in[2];
    const float* co      = (const float*)d_in[3];
    const float* W       = (const float*)d_in[4];
    const float* wb      = (const float*)d_in[5];
    const float* gb      = (const float*)d_in[6];
    const float* attn_w  = (const float*)d_in[7];
    // d_in[8] = attn_w_bias: cancels in softmax, unused
    const float* gate_w  = (const float*)d_in[9];
    const float* gate_wb = (const float*)d_in[10];
    const float* gate_b  = (const float*)d_in[11];

    _Float16* Pr  = (_Float16*)d_ws;
    _Float16* PES = (_Float16*)((char*)d_ws + 1000000);

    precompute_kernel<<<(NENT * 50 + 255) / 256, 256, 0, stream>>>(
        sym, W, wb, gb, Pr, PES);

    main_kernel<<<BB, 256, 0, stream>>>(
        conn, target, sym, co, Pr, PES,
        attn_w, gate_w, gate_wb, gate_b, (float*)d_out);
}

// Round 7
// 65.909 us; speedup vs baseline: 1.7655x; 1.0667x over previous
//
#include <hip/hip_runtime.h>

// Problem constants
#define BB   4096
#define MM   200
#define DD   100
#define NENT 5000
#define LPW  27     // logit-partial row stride (f32, odd -> ~2-way max aliasing)
#define PTW  101    // final-partial row stride (f32, odd)

typedef _Float16 f16x2 __attribute__((ext_vector_type(2)));
typedef unsigned uint2v __attribute__((ext_vector_type(2)));

#if defined(__has_builtin)
#if __has_builtin(__builtin_amdgcn_fdot2)
#define HAS_FDOT2 1
#endif
#endif

__device__ __forceinline__ f16x2 uh(unsigned u) { return __builtin_bit_cast(f16x2, u); }
__device__ __forceinline__ float2 h2f(f16x2 h) { return make_float2((float)h.x, (float)h.y); }

// ws layout (bytes):
//   Pr  : f16[5000][100] @ 0         = sym@W[:, :D]^T + (gcn_w_bias+gcn_b)
//   PES : f16[5000][200] @ 1,000,000 = [Pe row | sym row] per entity

// ---------------------------------------------------------------------------
// Kernel A: project the 5000 usable symbol rows through both halves of W.
// ---------------------------------------------------------------------------
__global__ __launch_bounds__(256) void precompute_kernel(
    const float* __restrict__ sym, const float* __restrict__ W,
    const float* __restrict__ wb, const float* __restrict__ gb,
    _Float16* __restrict__ Pr, _Float16* __restrict__ PES)
{
    __shared__ _Float16 Wt[200 * 102];
    const int tid = threadIdx.x;
    for (int j = tid; j < 20000; j += 256) {
        int d = j / 200, k = j % 200;
        Wt[k * 102 + d] = (_Float16)W[j];
    }
    __syncthreads();

    const int i = blockIdx.x * 256 + tid;
    if (i >= NENT * 50) return;
    const int e = i / 50, dp = i % 50;
    const float* se = sym + e * DD;

    float pr0 = 0.f, pr1 = 0.f, pe0 = 0.f, pe1 = 0.f;
    for (int k = 0; k < 100; k++) {
        float a = se[k];
        f16x2 w01 = *(const f16x2*)&Wt[k * 102 + 2 * dp];
        f16x2 w23 = *(const f16x2*)&Wt[(k + 100) * 102 + 2 * dp];
        pr0 = fmaf(a, (float)w01.x, pr0);
        pr1 = fmaf(a, (float)w01.y, pr1);
        pe0 = fmaf(a, (float)w23.x, pe0);
        pe1 = fmaf(a, (float)w23.y, pe1);
    }
    const int d0 = 2 * dp;
    pr0 += wb[d0]     + gb[d0];
    pr1 += wb[d0 + 1] + gb[d0 + 1];

    *(f16x2*)&Pr[e * DD + d0]           = f16x2{(_Float16)pr0, (_Float16)pr1};
    *(f16x2*)&PES[e * 2 * DD + d0]      = f16x2{(_Float16)pe0, (_Float16)pe1};
    *(f16x2*)&PES[e * 2 * DD + DD + d0] = f16x2{(_Float16)se[d0], (_Float16)se[d0 + 1]};
}

// ---------------------------------------------------------------------------
// Kernel B: one block per batch row, SINGLE pass (no m-chunking).
// Thread map: t = g*25 + dq, g in [0,10), dq in [0,25) -> d = 4dq..4dq+3.
// Phase 2: one unrolled sweep over all 200 m; x kept in 20 uint2v registers;
//   logit partials -> lp_s; neighbor sum fused (co_s written pre-S0).
// One softmax round (6 barriers total per block).
// Phase 4: register-only weighted sum, weights broadcast from ev_s.
// ---------------------------------------------------------------------------
__global__ __launch_bounds__(256, 4) void main_kernel(
    const int*  __restrict__ conn, const int* __restrict__ target,
    const float* __restrict__ sym, const float* __restrict__ co,
    const _Float16* __restrict__ Pr, const _Float16* __restrict__ PES,
    const float* __restrict__ attn_w,
    const float* __restrict__ gate_w, const float* __restrict__ gate_wb,
    const float* __restrict__ gate_b,
    float* __restrict__ outp)
{
    __shared__ float    scratch[MM * LPW];   // 21.6 KB: lp_s, later part[20][PTW]
    __shared__ unsigned idx_s[MM];           // rel | ent<<16
    __shared__ float    co_s[MM];
    __shared__ float    ev_s[MM];
    __shared__ float    red[8];
    float* lp_s = scratch;
    float* part = scratch;                   // aliased (last lp read pre-barB)

    const int t = threadIdx.x;
    const int b = blockIdx.x;
    const int* cb = conn + b * (MM * 3);
    const int lane = t & 63, wid = t >> 6;

    // ---- indices + scattered co gather (co_s needed in phase 2 -> pre-S0)
    if (t < MM) {
        int r = cb[t * 3 + 1];
        int e = cb[t * 3 + 2];
        idx_s[t] = (unsigned)r | ((unsigned)e << 16);
        int tgt = target[b * 2];                     // uniform
        co_s[t] = co[(long)e * NENT + tgt];          // scattered (L3)
    }
    __syncthreads();                                 // S0

    const int g = t / 25, dq = t % 25;
    const bool act = (t < 250);

    float4 awf = *(const float4*)&attn_w[4 * dq];
#ifdef HAS_FDOT2
    f16x2 aw01 = f16x2{(_Float16)awf.x, (_Float16)awf.y};
    f16x2 aw23 = f16x2{(_Float16)awf.z, (_Float16)awf.w};
#endif
    const _Float16 slope = (_Float16)0.01f;

    f16x2 nb01 = f16x2{(_Float16)0.f, (_Float16)0.f};
    f16x2 nb23 = nb01;
    uint2v xs[20];                                   // packed f16 x, all 200 m

    // ---- Phase 2: single unrolled sweep, 60 pipelined L2 loads
    if (act) {
        #pragma unroll
        for (int it = 0; it < 20; ++it) {
            int m = g + 10 * it;
            unsigned ir = idx_s[m];
            int r = ir & 0xffff, e = ir >> 16;
            uint2v pru = *(const uint2v*)(Pr + r * DD + 4 * dq);
            uint2v peu = *(const uint2v*)(PES + e * 2 * DD + 4 * dq);
            uint2v syu = *(const uint2v*)(PES + e * 2 * DD + DD + 4 * dq);
            f16x2 x01 = uh(pru.x) + uh(peu.x);
            f16x2 x23 = uh(pru.y) + uh(peu.y);
            x01 = __builtin_elementwise_max(x01, x01 * slope);  // leaky relu
            x23 = __builtin_elementwise_max(x23, x23 * slope);
            xs[it].x = __builtin_bit_cast(unsigned, x01);
            xs[it].y = __builtin_bit_cast(unsigned, x23);
            float lp;
#ifdef HAS_FDOT2
            lp = __builtin_amdgcn_fdot2(x01, aw01, 0.0f, false);
            lp = __builtin_amdgcn_fdot2(x23, aw23, lp, false);
#else
            float2 f01 = h2f(x01), f23 = h2f(x23);
            lp = f01.x * awf.x + f01.y * awf.y + f23.x * awf.z + f23.y * awf.w;
#endif
            lp_s[m * LPW + dq] = lp;
            _Float16 coh = (_Float16)co_s[m];
            f16x2 co2 = f16x2{coh, coh};
            nb01 = co2 * uh(syu.x) + nb01;
            nb23 = co2 * uh(syu.y) + nb23;
        }
    }
    __syncthreads();                                 // A: lp_s ready

    // ---- logits finish: thread = m, 25 partials per row (stride 27: free)
    float logit = -3.0e38f;
    if (t < MM) {
        const float* row = &lp_s[t * LPW];
        float s0 = (row[0] + row[1]) + (row[2] + row[3]);
        float s1 = (row[4] + row[5]) + (row[6] + row[7]);
        float s2 = (row[8] + row[9]) + (row[10] + row[11]);
        float s3 = (row[12] + row[13]) + (row[14] + row[15]);
        float s4 = (row[16] + row[17]) + (row[18] + row[19]);
        float s5 = (row[20] + row[21]) + (row[22] + row[23]);
        logit = ((s0 + s1) + (s2 + s3)) + ((s4 + s5) + row[24]);
    }
    // attn_b omitted: constant shift cancels in softmax

    // ---- single softmax round
    float v = logit;
    for (int off = 32; off >= 1; off >>= 1) v = fmaxf(v, __shfl_xor(v, off));
    if (lane == 0) red[wid] = v;
    __syncthreads();                                 // B: max partials
    float gmax = fmaxf(fmaxf(red[0], red[1]), fmaxf(red[2], red[3]));
    float ev = (t < MM) ? __expf(logit - gmax) : 0.f;
    if (t < MM) ev_s[t] = ev;
    float s = ev;
    for (int off = 32; off >= 1; off >>= 1) s += __shfl_xor(s, off);
    if (lane == 0) red[4 + wid] = s;
    __syncthreads();                                 // C: ev_s + sum ready
    float gsum = (red[4] + red[5]) + (red[6] + red[7]);

    // ---- Phase 4: register-only weighted sum, weights from ev_s (broadcast)
    float oa0 = 0.f, oa1 = 0.f, oa2 = 0.f, oa3 = 0.f;
    if (act) {
        #pragma unroll
        for (int it = 0; it < 20; ++it) {
            int m = g + 10 * it;
            float w = ev_s[m];
            float2 f01 = h2f(uh(xs[it].x));
            float2 f23 = h2f(uh(xs[it].y));
            oa0 = fmaf(w, f01.x, oa0);
            oa1 = fmaf(w, f01.y, oa1);
            oa2 = fmaf(w, f23.x, oa2);
            oa3 = fmaf(w, f23.y, oa3);
        }
    }
    float inv = 1.f / gsum;
    oa0 *= inv; oa1 *= inv; oa2 *= inv; oa3 *= inv;

    // ---- 10-way g-reduction (part aliases lp_s; all lp reads done pre-B)
    if (act) {
        float* po = &part[g * PTW + 4 * dq];
        po[0] = oa0; po[1] = oa1; po[2] = oa2; po[3] = oa3;
        float2 n01 = h2f(nb01), n23 = h2f(nb23);
        float* pn = &part[(10 + g) * PTW + 4 * dq];
        pn[0] = n01.x; pn[1] = n01.y; pn[2] = n23.x; pn[3] = n23.y;
    }
    __syncthreads();                                 // F

    float oaf = 0.f, nbf = 0.f;
    if (t < DD) {
        #pragma unroll
        for (int g2 = 0; g2 < 10; ++g2) {
            oaf += part[g2 * PTW + t];
            nbf += part[(10 + g2) * PTW + t];
        }
    }

    // ---- gate = sigmoid(dot(oaf, gate_w) + gwb + gb)
    float p = (t < DD) ? oaf * gate_w[t] : 0.f;
    for (int off = 32; off >= 1; off >>= 1) p += __shfl_xor(p, off);
    if (lane == 0) red[wid] = p;
    __syncthreads();                                 // G
    float dot = (red[0] + red[1]) + (red[2] + red[3]);
    float gt = 1.f / (1.f + __expf(-(dot + gate_wb[0] + gate_b[0])));

    if (t < DD) {
        float self_v = sym[cb[0] * DD + t];          // f32, exact
        outp[b * DD + t] = oaf * gt + self_v * (1.f - gt) + nbf;
    }
}

extern "C" void kernel_launch(void* const* d_in, const int* in_sizes, int n_in,
                              void* d_out, int out_size, void* d_ws, size_t ws_size,
                              hipStream_t stream) {
    const int*   conn    = (const int*)  d_in[0];
    const int*   target  = (const int*)  d_in[1];
    const float* sym     = (const float*)d_in[2];
    const float* co      = (const float*)d_in[3];
    const float* W       = (const float*)d_in[4];
    const float* wb      = (const float*)d_in[5];
    const float* gb      = (const float*)d_in[6];
    const float* attn_w  = (const float*)d_in[7];
    // d_in[8] = attn_w_bias: cancels in softmax, unused
    const float* gate_w  = (const float*)d_in[9];
    const float* gate_wb = (const float*)d_in[10];
    const float* gate_b  = (const float*)d_in[11];

    _Float16* Pr  = (_Float16*)d_ws;
    _Float16* PES = (_Float16*)((char*)d_ws + 1000000);

    precompute_kernel<<<(NENT * 50 + 255) / 256, 256, 0, stream>>>(
        sym, W, wb, gb, Pr, PES);

    main_kernel<<<BB, 256, 0, stream>>>(
        conn, target, sym, co, Pr, PES,
        attn_w, gate_w, gate_wb, gate_b, (float*)d_out);
}